// Round 23
// baseline (154.303 us; speedup 1.0000x reference)
//
#include <hip/hip_runtime.h>
#include <math.h>

#define NATOM_FEAT 24   // IPSIN * NWAVE = 3*8
#define PORI 13
#define NW 8
#define CAP 64          // bucket capacity per atom (max Poisson(25) degree ~47)
#define CH 32           // edges per LDS chunk (per wave)
#define ANG_T 34        // transposed ang stride [13][34]: even, 8B-aligned pair reads
#define OG_S 26         // ls_og stride (even -> 8B-aligned float2; 2-way = free)
#define WSLICE (PORI * ANG_T + CH * OG_S)   // 442 + 832 = 1274 floats (5096 B)
#define HID 128

typedef float vfloat4 __attribute__((ext_vector_type(4)));   // clang-native for nontemporal

// wave-local LDS sync: waits own wave's DS ops; "memory" clobber pins ordering
#define WAVE_SYNC() do { asm volatile("s_waitcnt lgkmcnt(0)" ::: "memory"); \
                         __builtin_amdgcn_wave_barrier(); } while (0)

__global__ void zero_k(int* __restrict__ p, int n)
{
    int i = blockIdx.x * blockDim.x + threadIdx.x;
    if (i < n) p[i] = 0;
}

// pack cart + species into float4 {x,y,z,species-bits}
__global__ void cart4_k(const float* __restrict__ cart, const int* __restrict__ species,
                        float4* __restrict__ cart4, int A)
{
    int i = blockIdx.x * blockDim.x + threadIdx.x;
    if (i < A)
        cart4[i] = make_float4(cart[3*i], cart[3*i+1], cart[3*i+2],
                               __int_as_float(species[i]));
}

// ---------------- fused bucket-CSR fill: full 64B slot write per edge ----------------
// slot i (64B) = [0]{dx,dy,dz,n} [1]{g0..g3} [2]{g4..g7} [3] pad (written for full line)
__global__ void fill_k(const int* __restrict__ nl,
                       int* __restrict__ cursor,
                       const float4* __restrict__ cart4,
                       const float* __restrict__ shifts,
                       const float* __restrict__ g_rs,
                       const float* __restrict__ g_inta,
                       const float* __restrict__ g_par,
                       float4* __restrict__ slots,
                       int E)
{
    __shared__ float s_rs[32], s_in[32], s_pa[32];
    if (threadIdx.x < 32) {
        s_rs[threadIdx.x] = g_rs[threadIdx.x];
        s_in[threadIdx.x] = g_inta[threadIdx.x];
        s_pa[threadIdx.x] = g_par[threadIdx.x];
    }
    __syncthreads();
    int e = blockIdx.x * blockDim.x + threadIdx.x;
    if (e >= E) return;
    int c = nl[e];
    int n = nl[E + e];
    float4 cc = cart4[c];          // 1 random 16B gather
    float4 cn = cart4[n];          // 1 random 16B gather (species rides in .w)
    float dx = cc.x - cn.x - shifts[3*e+0];
    float dy = cc.y - cn.y - shifts[3*e+1];
    float dz = cc.z - cn.z - shifts[3*e+2];
    float r  = sqrtf(dx*dx + dy*dy + dz*dz);
    float fcb = 0.5f * cosf(r * 0.6283185307179586f) + 0.5f;   // pi/5
    float fc  = fcb * fcb;
    int sb = __float_as_int(cn.w) * NW;
    float g[NW];
    #pragma unroll
    for (int w = 0; w < NW; ++w) {
        float dr = r - s_rs[sb + w];
        g[w] = __expf(-s_in[sb + w] * dr * dr) * s_pa[sb + w] * fc;
    }
    int ofs = atomicAdd(&cursor[c], 1);
    if (ofs < CAP) {
        vfloat4* sp = (vfloat4*)(slots + ((size_t)c * CAP + ofs) * 4);
        vfloat4 v0 = { dx, dy, dz, __int_as_float(n) };
        vfloat4 v1 = { g[0], g[1], g[2], g[3] };
        vfloat4 v2 = { g[4], g[5], g[6], g[7] };
        vfloat4 v3 = { 0.f, 0.f, 0.f, 0.f };
        __builtin_nontemporal_store(v0, sp + 0);
        __builtin_nontemporal_store(v1, sp + 1);
        __builtin_nontemporal_store(v2, sp + 2);
        __builtin_nontemporal_store(v3, sp + 3);
    }
}

// ---------------- fused per-atom pass: 4 independent waves/block, paired features ----
// ang TRANSPOSED [13][34]: one b64 read = ang for TWO edges -> 3 LDS issues / 2 edges.
// og pairs in permuted layout (1 b64/edge). LDS rule: broadcast reads b32/b64 only.
template<bool HASOUT, bool MLP>
__global__ __launch_bounds__(256, 8)
void atom_pass(const float4* __restrict__ slots,   // [A*CAP][4] float4
               const int* __restrict__ cursor,     // per-atom edge count
               const float* __restrict__ outp_in,  // [A,24] if HASOUT
               const float* __restrict__ w1, const float* __restrict__ b1,
               const float* __restrict__ w2, const float* __restrict__ b2,
               float* __restrict__ out,            // [A,24]: mlp out (MLP) or density
               int A)
{
    __shared__ __align__(16) float smem[4 * WSLICE];   // 20384 B -> 8 blocks/CU
    int lane = threadIdx.x & 63;
    int wid  = threadIdx.x >> 6;
    float* ls = smem + wid * WSLICE;      // wave-private slice
    float* ls_angT = ls;                  // [13][34] transposed
    float* ls_og   = ls + PORI * ANG_T;   // [CH][26] (24 used, permuted w-layout)
    // tail aliases (K-loop LDS dead after WAVE_SYNC):
    float* orb_s = ls;                    // [104]
    float* dvec  = ls + 104;              // [24]
    float* tvec  = ls + 128;              // [128]

    int a = blockIdx.x * 4 + wid;
    if (a >= A) return;
    int cnt = min(cursor[a], CAP);

    int p  = lane >> 2, wq = lane & 3;    // valid for lane < 52
    int ip = (p == 0) ? 0 : ((p < 4) ? 1 : 2);
    int ogb = ip * NW + 2 * wq;           // adjacent pair (wq, wq+4) in permuted layout

    float acc0 = 0.0f, acc1 = 0.0f;

    for (int s = 0; s < cnt; s += CH) {
        int m  = min(CH, cnt - s);
        int mm = (m + 1) & ~1;            // pad to even for paired ang reads
        if (lane < mm) {
            bool valid = (lane < m);
            float4 D = make_float4(0.f, 0.f, 0.f, __int_as_float(0));
            float4 G = make_float4(0.f, 0.f, 0.f, 0.f);
            float4 H = G;
            if (valid) {
                size_t si = ((size_t)a * CAP + s + lane) * 4;
                D = slots[si + 0];
                G = slots[si + 1];
                H = slots[si + 2];
            }
            float go[NW] = { G.x, G.y, G.z, G.w, H.x, H.y, H.z, H.w };
            float ax = D.x, ay = D.y, az = D.z;

            // transposed ang: row r, column lane (lane-consecutive writes, conflict-free)
            ls_angT[0*ANG_T  + lane] = valid ? 1.0f : 0.0f;
            ls_angT[1*ANG_T  + lane] = ax;
            ls_angT[2*ANG_T  + lane] = ay;
            ls_angT[3*ANG_T  + lane] = az;
            ls_angT[4*ANG_T  + lane] = ax*ax;
            ls_angT[5*ANG_T  + lane] = ax*ay;
            ls_angT[6*ANG_T  + lane] = ax*az;
            ls_angT[7*ANG_T  + lane] = ay*ax;
            ls_angT[8*ANG_T  + lane] = ay*ay;
            ls_angT[9*ANG_T  + lane] = ay*az;
            ls_angT[10*ANG_T + lane] = az*ax;
            ls_angT[11*ANG_T + lane] = az*ay;
            ls_angT[12*ANG_T + lane] = az*az;

            // permuted og: value(i, w) at i*8 + (w<4 ? 2w : 2(w-4)+1); pad lane writes zeros
            float2* ogr = (float2*)(ls_og + lane * OG_S);
            if (HASOUT) {
                int n = __float_as_int(D.w);   // pad lane: n=0, go=0 -> writes zeros
                const float4* orow = (const float4*)(outp_in + (size_t)n * NATOM_FEAT);
                float4 o0 = orow[0], o1 = orow[1], o2 = orow[2];
                float4 o3 = orow[3], o4 = orow[4], o5 = orow[5];
                const float* oa = (const float*)&o0;   // i=0, w=0..3
                const float* ob = (const float*)&o1;   // i=0, w=4..7
                const float* oc = (const float*)&o2;   // i=1, w=0..3
                const float* od = (const float*)&o3;   // i=1, w=4..7
                const float* oe = (const float*)&o4;   // i=2, w=0..3
                const float* of = (const float*)&o5;   // i=2, w=4..7
                #pragma unroll
                for (int q = 0; q < 4; ++q) {
                    ogr[q]     = make_float2(go[q]*oa[q], go[q+4]*ob[q]);
                    ogr[4 + q] = make_float2(go[q]*oc[q], go[q+4]*od[q]);
                    ogr[8 + q] = make_float2(go[q]*oe[q], go[q+4]*of[q]);
                }
            } else {
                #pragma unroll
                for (int q = 0; q < 4; ++q) {
                    float2 v = make_float2(go[q], go[q+4]);
                    ogr[q] = v; ogr[4 + q] = v; ogr[8 + q] = v;
                }
            }
        }
        WAVE_SYNC();                       // staged data visible to whole wave
        if (lane < 52) {
            int mp = mm >> 1;
            const float* angRow = ls_angT + p * ANG_T;
            for (int t = 0; t < mp; ++t) {
                float2 av  = *(const float2*)(angRow + 2*t);            // ang 2 edges
                float2 ov0 = *(const float2*)(ls_og + (2*t)   * OG_S + ogb);
                float2 ov1 = *(const float2*)(ls_og + (2*t+1) * OG_S + ogb);
                acc0 += av.x * ov0.x + av.y * ov1.x;
                acc1 += av.x * ov0.y + av.y * ov1.y;
            }
        }
        WAVE_SYNC();                       // reads retired before slice is overwritten
    }

    // orbital^2 -> aliased LDS (features f0=p*8+wq, f1=p*8+wq+4)
    if (lane < 52) {
        orb_s[p * NW + wq]     = acc0 * acc0;
        orb_s[p * NW + wq + 4] = acc1 * acc1;
    }
    WAVE_SYNC();

    if (lane < NATOM_FEAT) {
        int i = lane >> 3, ww = lane & 7;
        float sum;
        if (i == 0) {
            sum = orb_s[ww];
        } else if (i == 1) {
            sum = orb_s[NW + ww] + orb_s[2*NW + ww] + orb_s[3*NW + ww];
        } else {
            sum = 0.0f;
            #pragma unroll
            for (int q = 4; q < PORI; ++q) sum += orb_s[q*NW + ww];
        }
        if (MLP) dvec[lane] = sum;
        else     out[(size_t)a * NATOM_FEAT + lane] = sum;
    }

    if (MLP) {
        WAVE_SYNC();
        // phase B: lane handles hidden units h=lane and h=lane+64
        float h0 = b1[lane], h1 = b1[lane + 64];
        #pragma unroll
        for (int j = 0; j < NATOM_FEAT; ++j) {
            float d = dvec[j];                       // broadcast
            h0 += d * w1[j * HID + lane];            // coalesced, L1-hot
            h1 += d * w1[j * HID + lane + 64];
        }
        float e0 = __expf(2.0f * h0), e1 = __expf(2.0f * h1);
        tvec[lane]      = 1.0f - 2.0f / (e0 + 1.0f);
        tvec[lane + 64] = 1.0f - 2.0f / (e1 + 1.0f);
        WAVE_SYNC();
        // phase C: lanes 0..47 = (j = lane%24, h-half = lane/24); combine via shuffle
        int j  = (lane < 24) ? lane : lane - 24;
        int hb = (lane < 24) ? 0 : 64;
        float part = 0.0f;
        if (lane < 48) {
            #pragma unroll 8
            for (int h = 0; h < 64; ++h)
                part += tvec[hb + h] * w2[(hb + h) * NATOM_FEAT + j];
        }
        float other = __shfl(part, lane + 24);
        if (lane < NATOM_FEAT)
            out[(size_t)a * NATOM_FEAT + lane] = b2[lane] + part + other;
    }
}

extern "C" void kernel_launch(void* const* d_in, const int* in_sizes, int n_in,
                              void* d_out, int out_size, void* d_ws, size_t ws_size,
                              hipStream_t stream)
{
    const float* cart    = (const float*)d_in[0];
    const int*   nl      = (const int*)d_in[1];
    const float* shifts  = (const float*)d_in[2];
    const int*   species = (const int*)d_in[3];
    const float* rs      = (const float*)d_in[4];
    const float* inta    = (const float*)d_in[5];
    const float* params  = (const float*)d_in[6];
    const float* w1_0 = (const float*)d_in[7];
    const float* b1_0 = (const float*)d_in[8];
    const float* w2_0 = (const float*)d_in[9];
    const float* b2_0 = (const float*)d_in[10];
    const float* w1_1 = (const float*)d_in[11];
    const float* b1_1 = (const float*)d_in[12];
    const float* w2_1 = (const float*)d_in[13];
    const float* b2_1 = (const float*)d_in[14];

    const int A = in_sizes[0] / 3;
    const int E = in_sizes[1] / 2;

    // workspace layout — 64B slot array first (A*CAP*64B = 82 MB), then small arrays
    char* ws = (char*)d_ws;
    float4* slots = (float4*)ws;              ws += (size_t)A * CAP * 64;
    float4* cart4 = (float4*)ws;              ws += (size_t)A * 16;
    int*   cursor = (int*)ws;                 ws += (size_t)A * 4;
    float* outpA  = (float*)ws;               ws += (size_t)A * NATOM_FEAT * 4;
    float* outpB  = (float*)ws;               ws += (size_t)A * NATOM_FEAT * 4;
    float* dout   = (float*)d_out;

    const int BLK = 256;
    const int gridE = (E + BLK - 1) / BLK;
    const int gridA = (A + BLK - 1) / BLK;
    const int gridP = (A + 3) / 4;

    // ---- bucket-CSR build ----
    zero_k<<<gridA, BLK, 0, stream>>>(cursor, A);
    cart4_k<<<gridA, BLK, 0, stream>>>(cart, species, cart4, A);
    fill_k<<<gridE, BLK, 0, stream>>>(nl, cursor, cart4, shifts,
                                      rs, inta, params, slots, E);

    // ---- pass 0 (+ MLP0) -> outpA ----
    atom_pass<false, true><<<gridP, 256, 0, stream>>>(slots, cursor,
                                                      nullptr, w1_0, b1_0, w2_0, b2_0, outpA, A);
    // ---- pass 1 (+ MLP1) -> outpB ----
    atom_pass<true, true><<<gridP, 256, 0, stream>>>(slots, cursor,
                                                     outpA, w1_1, b1_1, w2_1, b2_1, outpB, A);
    // ---- pass 2 (density only) -> d_out ----
    atom_pass<true, false><<<gridP, 256, 0, stream>>>(slots, cursor,
                                                      outpB, nullptr, nullptr, nullptr, nullptr, dout, A);
}

// Round 24
// 115.273 us; speedup vs baseline: 1.3386x; 1.3386x over previous
//
#include <hip/hip_runtime.h>
#include <math.h>

#define NATOM_FEAT 24   // IPSIN * NWAVE = 3*8
#define PORI 13
#define NW 8
#define CAP 64          // bucket capacity per atom (max Poisson(25) degree ~47)
#define CH 32           // edges per LDS chunk (per wave)
#define ANG_T 34        // transposed ang stride [13][34]: even, 8B-aligned pair reads
#define OG_S 26         // ls_og stride (even -> 8B-aligned float2; 2-way = free)
#define WSLICE (PORI * ANG_T + CH * OG_S)   // 442 + 832 = 1274 floats (5096 B)
#define HID 128

// wave-local LDS sync: waits own wave's DS ops; "memory" clobber pins ordering
#define WAVE_SYNC() do { asm volatile("s_waitcnt lgkmcnt(0)" ::: "memory"); \
                         __builtin_amdgcn_wave_barrier(); } while (0)

__global__ void zero_k(int* __restrict__ p, int n)
{
    int i = blockIdx.x * blockDim.x + threadIdx.x;
    if (i < n) p[i] = 0;
}

// pack cart + species into float4 {x,y,z,species-bits}
__global__ void cart4_k(const float* __restrict__ cart, const int* __restrict__ species,
                        float4* __restrict__ cart4, int A)
{
    int i = blockIdx.x * blockDim.x + threadIdx.x;
    if (i < A)
        cart4[i] = make_float4(cart[3*i], cart[3*i+1], cart[3*i+2],
                               __int_as_float(species[i]));
}

// ---------------- fused bucket-CSR fill: 48B slot write per edge (PLAIN stores) ----------
// slot i (64B region) = [0]{dx,dy,dz,n} [1]{g0..g3} [2]{g4..g7} ([3] untouched pad)
__global__ void fill_k(const int* __restrict__ nl,
                       int* __restrict__ cursor,
                       const float4* __restrict__ cart4,
                       const float* __restrict__ shifts,
                       const float* __restrict__ g_rs,
                       const float* __restrict__ g_inta,
                       const float* __restrict__ g_par,
                       float4* __restrict__ slots,
                       int E)
{
    __shared__ float s_rs[32], s_in[32], s_pa[32];
    if (threadIdx.x < 32) {
        s_rs[threadIdx.x] = g_rs[threadIdx.x];
        s_in[threadIdx.x] = g_inta[threadIdx.x];
        s_pa[threadIdx.x] = g_par[threadIdx.x];
    }
    __syncthreads();
    int e = blockIdx.x * blockDim.x + threadIdx.x;
    if (e >= E) return;
    int c = nl[e];
    int n = nl[E + e];
    float4 cc = cart4[c];          // 1 random 16B gather
    float4 cn = cart4[n];          // 1 random 16B gather (species rides in .w)
    float dx = cc.x - cn.x - shifts[3*e+0];
    float dy = cc.y - cn.y - shifts[3*e+1];
    float dz = cc.z - cn.z - shifts[3*e+2];
    float r  = sqrtf(dx*dx + dy*dy + dz*dz);
    float fcb = 0.5f * cosf(r * 0.6283185307179586f) + 0.5f;   // pi/5
    float fc  = fcb * fcb;
    int sb = __float_as_int(cn.w) * NW;
    float g[NW];
    #pragma unroll
    for (int w = 0; w < NW; ++w) {
        float dr = r - s_rs[sb + w];
        g[w] = __expf(-s_in[sb + w] * dr * dr) * s_pa[sb + w] * fc;
    }
    int ofs = atomicAdd(&cursor[c], 1);
    if (ofs < CAP) {
        size_t si = ((size_t)c * CAP + ofs) * 4;
        slots[si + 0] = make_float4(dx, dy, dz, __int_as_float(n));
        slots[si + 1] = make_float4(g[0], g[1], g[2], g[3]);
        slots[si + 2] = make_float4(g[4], g[5], g[6], g[7]);
    }
}

// ---------------- fused per-atom pass: 4 independent waves/block, paired features ----
// ang TRANSPOSED [13][34]: one b64 read = ang for TWO edges -> 3 LDS issues / 2 edges.
// og pairs in permuted layout (1 b64/edge). LDS rule: broadcast reads b32/b64 only.
template<bool HASOUT, bool MLP>
__global__ __launch_bounds__(256, 8)
void atom_pass(const float4* __restrict__ slots,   // [A*CAP][4] float4
               const int* __restrict__ cursor,     // per-atom edge count
               const float* __restrict__ outp_in,  // [A,24] if HASOUT
               const float* __restrict__ w1, const float* __restrict__ b1,
               const float* __restrict__ w2, const float* __restrict__ b2,
               float* __restrict__ out,            // [A,24]: mlp out (MLP) or density
               int A)
{
    __shared__ __align__(16) float smem[4 * WSLICE];   // 20384 B -> 8 blocks/CU
    int lane = threadIdx.x & 63;
    int wid  = threadIdx.x >> 6;
    float* ls = smem + wid * WSLICE;      // wave-private slice
    float* ls_angT = ls;                  // [13][34] transposed
    float* ls_og   = ls + PORI * ANG_T;   // [CH][26] (24 used, permuted w-layout)
    // tail aliases (K-loop LDS dead after WAVE_SYNC):
    float* orb_s = ls;                    // [104]
    float* dvec  = ls + 104;              // [24]
    float* tvec  = ls + 128;              // [128]

    int a = blockIdx.x * 4 + wid;
    if (a >= A) return;
    int cnt = min(cursor[a], CAP);

    int p  = lane >> 2, wq = lane & 3;    // valid for lane < 52
    int ip = (p == 0) ? 0 : ((p < 4) ? 1 : 2);
    int ogb = ip * NW + 2 * wq;           // adjacent pair (wq, wq+4) in permuted layout

    float acc0 = 0.0f, acc1 = 0.0f;

    for (int s = 0; s < cnt; s += CH) {
        int m  = min(CH, cnt - s);
        int mm = (m + 1) & ~1;            // pad to even for paired ang reads
        if (lane < mm) {
            bool valid = (lane < m);
            float4 D = make_float4(0.f, 0.f, 0.f, __int_as_float(0));
            float4 G = make_float4(0.f, 0.f, 0.f, 0.f);
            float4 H = G;
            if (valid) {
                size_t si = ((size_t)a * CAP + s + lane) * 4;
                D = slots[si + 0];
                G = slots[si + 1];
                H = slots[si + 2];
            }
            float go[NW] = { G.x, G.y, G.z, G.w, H.x, H.y, H.z, H.w };
            float ax = D.x, ay = D.y, az = D.z;

            // transposed ang: row r, column lane (lane-consecutive writes, conflict-free)
            ls_angT[0*ANG_T  + lane] = valid ? 1.0f : 0.0f;
            ls_angT[1*ANG_T  + lane] = ax;
            ls_angT[2*ANG_T  + lane] = ay;
            ls_angT[3*ANG_T  + lane] = az;
            ls_angT[4*ANG_T  + lane] = ax*ax;
            ls_angT[5*ANG_T  + lane] = ax*ay;
            ls_angT[6*ANG_T  + lane] = ax*az;
            ls_angT[7*ANG_T  + lane] = ay*ax;
            ls_angT[8*ANG_T  + lane] = ay*ay;
            ls_angT[9*ANG_T  + lane] = ay*az;
            ls_angT[10*ANG_T + lane] = az*ax;
            ls_angT[11*ANG_T + lane] = az*ay;
            ls_angT[12*ANG_T + lane] = az*az;

            // permuted og: value(i, w) at i*8 + (w<4 ? 2w : 2(w-4)+1); pad lane writes zeros
            float2* ogr = (float2*)(ls_og + lane * OG_S);
            if (HASOUT) {
                int n = __float_as_int(D.w);   // pad lane: n=0, go=0 -> writes zeros
                const float4* orow = (const float4*)(outp_in + (size_t)n * NATOM_FEAT);
                float4 o0 = orow[0], o1 = orow[1], o2 = orow[2];
                float4 o3 = orow[3], o4 = orow[4], o5 = orow[5];
                const float* oa = (const float*)&o0;   // i=0, w=0..3
                const float* ob = (const float*)&o1;   // i=0, w=4..7
                const float* oc = (const float*)&o2;   // i=1, w=0..3
                const float* od = (const float*)&o3;   // i=1, w=4..7
                const float* oe = (const float*)&o4;   // i=2, w=0..3
                const float* of = (const float*)&o5;   // i=2, w=4..7
                #pragma unroll
                for (int q = 0; q < 4; ++q) {
                    ogr[q]     = make_float2(go[q]*oa[q], go[q+4]*ob[q]);
                    ogr[4 + q] = make_float2(go[q]*oc[q], go[q+4]*od[q]);
                    ogr[8 + q] = make_float2(go[q]*oe[q], go[q+4]*of[q]);
                }
            } else {
                #pragma unroll
                for (int q = 0; q < 4; ++q) {
                    float2 v = make_float2(go[q], go[q+4]);
                    ogr[q] = v; ogr[4 + q] = v; ogr[8 + q] = v;
                }
            }
        }
        WAVE_SYNC();                       // staged data visible to whole wave
        if (lane < 52) {
            int mp = mm >> 1;
            const float* angRow = ls_angT + p * ANG_T;
            for (int t = 0; t < mp; ++t) {
                float2 av  = *(const float2*)(angRow + 2*t);            // ang 2 edges
                float2 ov0 = *(const float2*)(ls_og + (2*t)   * OG_S + ogb);
                float2 ov1 = *(const float2*)(ls_og + (2*t+1) * OG_S + ogb);
                acc0 += av.x * ov0.x + av.y * ov1.x;
                acc1 += av.x * ov0.y + av.y * ov1.y;
            }
        }
        WAVE_SYNC();                       // reads retired before slice is overwritten
    }

    // orbital^2 -> aliased LDS (features f0=p*8+wq, f1=p*8+wq+4)
    if (lane < 52) {
        orb_s[p * NW + wq]     = acc0 * acc0;
        orb_s[p * NW + wq + 4] = acc1 * acc1;
    }
    WAVE_SYNC();

    if (lane < NATOM_FEAT) {
        int i = lane >> 3, ww = lane & 7;
        float sum;
        if (i == 0) {
            sum = orb_s[ww];
        } else if (i == 1) {
            sum = orb_s[NW + ww] + orb_s[2*NW + ww] + orb_s[3*NW + ww];
        } else {
            sum = 0.0f;
            #pragma unroll
            for (int q = 4; q < PORI; ++q) sum += orb_s[q*NW + ww];
        }
        if (MLP) dvec[lane] = sum;
        else     out[(size_t)a * NATOM_FEAT + lane] = sum;
    }

    if (MLP) {
        WAVE_SYNC();
        // phase B: lane handles hidden units h=lane and h=lane+64
        float h0 = b1[lane], h1 = b1[lane + 64];
        #pragma unroll
        for (int j = 0; j < NATOM_FEAT; ++j) {
            float d = dvec[j];                       // broadcast
            h0 += d * w1[j * HID + lane];            // coalesced, L1-hot
            h1 += d * w1[j * HID + lane + 64];
        }
        float e0 = __expf(2.0f * h0), e1 = __expf(2.0f * h1);
        tvec[lane]      = 1.0f - 2.0f / (e0 + 1.0f);
        tvec[lane + 64] = 1.0f - 2.0f / (e1 + 1.0f);
        WAVE_SYNC();
        // phase C: lanes 0..47 = (j = lane%24, h-half = lane/24); combine via shuffle
        int j  = (lane < 24) ? lane : lane - 24;
        int hb = (lane < 24) ? 0 : 64;
        float part = 0.0f;
        if (lane < 48) {
            #pragma unroll 8
            for (int h = 0; h < 64; ++h)
                part += tvec[hb + h] * w2[(hb + h) * NATOM_FEAT + j];
        }
        float other = __shfl(part, lane + 24);
        if (lane < NATOM_FEAT)
            out[(size_t)a * NATOM_FEAT + lane] = b2[lane] + part + other;
    }
}

extern "C" void kernel_launch(void* const* d_in, const int* in_sizes, int n_in,
                              void* d_out, int out_size, void* d_ws, size_t ws_size,
                              hipStream_t stream)
{
    const float* cart    = (const float*)d_in[0];
    const int*   nl      = (const int*)d_in[1];
    const float* shifts  = (const float*)d_in[2];
    const int*   species = (const int*)d_in[3];
    const float* rs      = (const float*)d_in[4];
    const float* inta    = (const float*)d_in[5];
    const float* params  = (const float*)d_in[6];
    const float* w1_0 = (const float*)d_in[7];
    const float* b1_0 = (const float*)d_in[8];
    const float* w2_0 = (const float*)d_in[9];
    const float* b2_0 = (const float*)d_in[10];
    const float* w1_1 = (const float*)d_in[11];
    const float* b1_1 = (const float*)d_in[12];
    const float* w2_1 = (const float*)d_in[13];
    const float* b2_1 = (const float*)d_in[14];

    const int A = in_sizes[0] / 3;
    const int E = in_sizes[1] / 2;

    // workspace layout — 64B slot array first (A*CAP*64B = 82 MB), then small arrays
    char* ws = (char*)d_ws;
    float4* slots = (float4*)ws;              ws += (size_t)A * CAP * 64;
    float4* cart4 = (float4*)ws;              ws += (size_t)A * 16;
    int*   cursor = (int*)ws;                 ws += (size_t)A * 4;
    float* outpA  = (float*)ws;               ws += (size_t)A * NATOM_FEAT * 4;
    float* outpB  = (float*)ws;               ws += (size_t)A * NATOM_FEAT * 4;
    float* dout   = (float*)d_out;

    const int BLK = 256;
    const int gridE = (E + BLK - 1) / BLK;
    const int gridA = (A + BLK - 1) / BLK;
    const int gridP = (A + 3) / 4;

    // ---- bucket-CSR build ----
    zero_k<<<gridA, BLK, 0, stream>>>(cursor, A);
    cart4_k<<<gridA, BLK, 0, stream>>>(cart, species, cart4, A);
    fill_k<<<gridE, BLK, 0, stream>>>(nl, cursor, cart4, shifts,
                                      rs, inta, params, slots, E);

    // ---- pass 0 (+ MLP0) -> outpA ----
    atom_pass<false, true><<<gridP, 256, 0, stream>>>(slots, cursor,
                                                      nullptr, w1_0, b1_0, w2_0, b2_0, outpA, A);
    // ---- pass 1 (+ MLP1) -> outpB ----
    atom_pass<true, true><<<gridP, 256, 0, stream>>>(slots, cursor,
                                                     outpA, w1_1, b1_1, w2_1, b2_1, outpB, A);
    // ---- pass 2 (density only) -> d_out ----
    atom_pass<true, false><<<gridP, 256, 0, stream>>>(slots, cursor,
                                                      outpB, nullptr, nullptr, nullptr, nullptr, dout, A);
}